// Round 2
// baseline (1749.483 us; speedup 1.0000x reference)
//
#include <hip/hip_runtime.h>
#include <math.h>

#define EPS_C 0.001f
#define BATCH 16384

// ---------------- H = X^T X + eps*I  (1152x1152) ----------------
__global__ __launch_bounds__(256) void k_xtx(const float* __restrict__ X, float* __restrict__ H) {
  __shared__ float sA[32][65];
  __shared__ float sB[32][65];
  const int t = threadIdx.x;
  const int bi = blockIdx.x * 64, bj = blockIdx.y * 64;
  const int tj = t & 15, ti = t >> 4;
  float acc[4][4] = {};
  for (int k0 = 0; k0 < 1152; k0 += 32) {
    #pragma unroll
    for (int l = 0; l < 2; ++l) {
      int idx = t + l * 256;
      int kk = idx >> 4, c4 = (idx & 15) << 2;
      float4 va = *(const float4*)&X[(k0 + kk) * 1152 + bi + c4];
      sA[kk][c4 + 0] = va.x; sA[kk][c4 + 1] = va.y; sA[kk][c4 + 2] = va.z; sA[kk][c4 + 3] = va.w;
      float4 vb = *(const float4*)&X[(k0 + kk) * 1152 + bj + c4];
      sB[kk][c4 + 0] = vb.x; sB[kk][c4 + 1] = vb.y; sB[kk][c4 + 2] = vb.z; sB[kk][c4 + 3] = vb.w;
    }
    __syncthreads();
    #pragma unroll
    for (int kk = 0; kk < 32; ++kk) {
      float am[4], bn[4];
      #pragma unroll
      for (int q = 0; q < 4; ++q) am[q] = sA[kk][ti * 4 + q];
      #pragma unroll
      for (int q = 0; q < 4; ++q) bn[q] = sB[kk][tj * 4 + q];
      #pragma unroll
      for (int r = 0; r < 4; ++r)
        #pragma unroll
        for (int c = 0; c < 4; ++c)
          acc[r][c] = fmaf(am[r], bn[c], acc[r][c]);
    }
    __syncthreads();
  }
  #pragma unroll
  for (int r = 0; r < 4; ++r) {
    int gi = bi + ti * 4 + r;
    float vv[4];
    #pragma unroll
    for (int c = 0; c < 4; ++c) {
      vv[c] = acc[r][c];
      if (gi == bj + tj * 4 + c) vv[c] += EPS_C;
    }
    float4 o = make_float4(vv[0], vv[1], vv[2], vv[3]);
    *(float4*)&H[gi * 1152 + bj + tj * 4] = o;
  }
}

// ---------------- assemble M=[E^T | C2^T], D11, Lam, xc, Fx ----------------
__global__ void k_assemble(const float* __restrict__ H, const float* __restrict__ Y,
                           const float* __restrict__ C2, const float* __restrict__ x0,
                           float* __restrict__ M, float* __restrict__ D11,
                           float* __restrict__ Lam, float* __restrict__ xc, float* __restrict__ Fx) {
  int idx = blockIdx.x * 256 + threadIdx.x;
  if (idx < 262144) {
    int r = idx >> 9, c = idx & 511;
    M[r * 640 + c] = 0.5f * (H[c * 1152 + r] + H[(640 + c) * 1152 + 640 + r] + Y[c * 512 + r] - Y[r * 512 + c]);
  } else if (idx < 327680) {
    int q = idx - 262144;
    int r = q >> 7, o = q & 127;
    M[r * 640 + 512 + o] = C2[o * 512 + r];
  } else if (idx < 344064) {
    int q = idx - 327680;
    int i = q >> 7, j = q & 127;
    D11[q] = (j < i) ? -H[(512 + i) * 1152 + 512 + j] : 0.0f;
  } else if (idx < 344192) {
    int i = idx - 344064;
    Lam[i] = 0.5f * H[(512 + i) * 1152 + 512 + i];
  } else if (idx < 344320) {
    int i = idx - 344192;
    float s = 0.f;
    for (int a = 0; a < 512; ++a) s = fmaf(H[(512 + i) * 1152 + a], x0[a], s);
    xc[i] = -s;
  } else if (idx < 344832) {
    int r = idx - 344320;
    float s = 0.f;
    for (int b = 0; b < 512; ++b) s = fmaf(H[(640 + r) * 1152 + b], x0[b], s);
    Fx[r] = s;
  }
}

// ---------------- LU diag block factor (no pivoting) + U column-major copy + recip diag ----------------
__global__ __launch_bounds__(64) void k_lu_diag(float* __restrict__ M, float* __restrict__ Ut,
                                                float* __restrict__ rdU, int kb) {
  const int lane = threadIdx.x;
  float* blk = M + kb * 64 * 640 + kb * 64;
  float col[64];
  #pragma unroll
  for (int r = 0; r < 64; ++r) col[r] = blk[r * 640 + lane];
  float invp = 1.0f;
  #pragma unroll
  for (int k = 0; k < 64; ++k) {
    float piv = __shfl(col[k], k);
    float inv = 1.0f / piv;
    if (lane == k) invp = inv;
    float m = col[k] * inv;          // pivot row scaled (valid for lane > k)
    bool act = lane > k;
    #pragma unroll
    for (int r = k + 1; r < 64; ++r) {
      float ckr = __shfl(col[r], k); // pivot column element (unscaled)
      if (act) col[r] -= ckr * m;
    }
  }
  #pragma unroll
  for (int r = 0; r < 64; ++r) {
    if (r > lane) col[r] *= invp;    // scale L part of own column
    blk[r * 640 + lane] = col[r];
  }
  rdU[kb * 64 + lane] = invp;
  // lane = column j; write U column (rows 0..lane within block) to Ut (col-major)
  const int c = kb * 64 + lane;
  #pragma unroll
  for (int r = 0; r < 64; ++r)
    if (r <= lane) Ut[c * 512 + kb * 64 + r] = col[r];
}

// ---------------- panels: per-thread fully-unrolled 64-deep triangular solves ----------------
// U-panel (incl. augmented cols): solve unit-L * u = a per column
// L-panel: solve x * U = a per row
__global__ __launch_bounds__(64) void k_lu_panels(float* __restrict__ M, float* __restrict__ Ut, int kb) {
  __shared__ float sD[64 * 65];
  __shared__ float sRD[64];
  const int t = threadIdx.x;
  for (int l = 0; l < 64; ++l) sD[l * 65 + t] = M[(kb * 64 + l) * 640 + kb * 64 + t];
  __syncthreads();
  sRD[t] = 1.0f / sD[t * 65 + t];
  __syncthreads();
  const int nU = 9 - kb;
  const int b = blockIdx.x;
  if (b < nU) {
    const int c = 64 * (kb + 1) + b * 64 + t;
    float v[64];
    #pragma unroll
    for (int i = 0; i < 64; ++i) v[i] = M[(kb * 64 + i) * 640 + c];
    #pragma unroll
    for (int i = 1; i < 64; ++i) {
      float acc = v[i];
      #pragma unroll
      for (int j = 0; j < i; ++j) acc = fmaf(-sD[i * 65 + j], v[j], acc);
      v[i] = acc;
    }
    #pragma unroll
    for (int i = 0; i < 64; ++i) M[(kb * 64 + i) * 640 + c] = v[i];
    if (c < 512) {
      #pragma unroll
      for (int i = 0; i < 64; ++i) Ut[c * 512 + kb * 64 + i] = v[i];
    }
  } else {
    const int r = 64 * (kb + 1) + (b - nU) * 64 + t;
    float v[64];
    #pragma unroll
    for (int i = 0; i < 16; ++i) *(float4*)&v[i * 4] = *(const float4*)&M[r * 640 + kb * 64 + i * 4];
    #pragma unroll
    for (int j = 0; j < 64; ++j) {
      float acc = v[j];
      #pragma unroll
      for (int i = 0; i < j; ++i) acc = fmaf(-v[i], sD[i * 65 + j], acc);
      v[j] = acc * sRD[j];
    }
    #pragma unroll
    for (int i = 0; i < 16; ++i) *(float4*)&M[r * 640 + kb * 64 + i * 4] = *(float4*)&v[i * 4];
  }
}

// ---------------- trailing update: A22 -= L21 * U12 (cols include augmented) ----------------
__global__ __launch_bounds__(256) void k_lu_trailing(float* __restrict__ M, int kb) {
  __shared__ float sL[32][65]; // [k][m]
  __shared__ float sU[32][65]; // [k][n]
  const int t = threadIdx.x;
  const int base = 64 * (kb + 1);
  const int r0 = base + blockIdx.y * 64, c0 = base + blockIdx.x * 64;
  const int tj = t & 15, ti = t >> 4;
  float acc[4][4] = {};
  for (int k0 = 0; k0 < 64; k0 += 32) {
    #pragma unroll
    for (int l = 0; l < 2; ++l) {
      int idx = t + l * 256;
      int row = idx >> 3, k4 = (idx & 7) << 2;
      float4 v = *(const float4*)&M[(r0 + row) * 640 + kb * 64 + k0 + k4];
      sL[k4 + 0][row] = v.x; sL[k4 + 1][row] = v.y; sL[k4 + 2][row] = v.z; sL[k4 + 3][row] = v.w;
      int kk = idx >> 4, c4 = (idx & 15) << 2;
      float4 u4 = *(const float4*)&M[(kb * 64 + k0 + kk) * 640 + c0 + c4];
      sU[kk][c4 + 0] = u4.x; sU[kk][c4 + 1] = u4.y; sU[kk][c4 + 2] = u4.z; sU[kk][c4 + 3] = u4.w;
    }
    __syncthreads();
    #pragma unroll
    for (int kk = 0; kk < 32; ++kk) {
      float am[4], bn[4];
      #pragma unroll
      for (int q = 0; q < 4; ++q) am[q] = sL[kk][ti * 4 + q];
      #pragma unroll
      for (int q = 0; q < 4; ++q) bn[q] = sU[kk][tj * 4 + q];
      #pragma unroll
      for (int r = 0; r < 4; ++r)
        #pragma unroll
        for (int c = 0; c < 4; ++c)
          acc[r][c] = fmaf(am[r], bn[c], acc[r][c]);
    }
    __syncthreads();
  }
  #pragma unroll
  for (int r = 0; r < 4; ++r) {
    float4 old = *(float4*)&M[(r0 + ti * 4 + r) * 640 + c0 + tj * 4];
    old.x -= acc[r][0]; old.y -= acc[r][1]; old.z -= acc[r][2]; old.w -= acc[r][3];
    *(float4*)&M[(r0 + ti * 4 + r) * 640 + c0 + tj * 4] = old;
  }
}

// ---------------- backward solve U * Gt = Z (column-sweep, one wave per RHS) ----------------
__global__ __launch_bounds__(256) void k_trsm_bwd(const float* __restrict__ M, const float* __restrict__ Ut,
                                                  const float* __restrict__ rdU, float* __restrict__ Gt) {
  const int lane = threadIdx.x & 63;
  const int o = (blockIdx.x * 256 + threadIdx.x) >> 6; // 0..127
  float v[8];
  #pragma unroll
  for (int m = 0; m < 8; ++m) v[m] = M[(m * 64 + lane) * 640 + 512 + o];
  for (int i = 511; i >= 0; --i) {
    const int mi = i >> 6, li = i & 63;
    float xi = __shfl(v[mi] * rdU[i], li);
    const float* Uc = Ut + i * 512;
    for (int m = 0; m < mi; ++m) v[m] = fmaf(-Uc[m * 64 + lane], xi, v[m]);
    float um = Uc[mi * 64 + lane];
    if (lane < li) v[mi] = fmaf(-um, xi, v[mi]);
    else if (lane == li) v[mi] = xi;
  }
  #pragma unroll
  for (int m = 0; m < 8; ++m) Gt[(m * 64 + lane) * 128 + o] = v[m];
}

// ---------------- W1 = G@B1 + D21, W2 = G@B2 + D22, bias = G@Fx ----------------
__global__ void k_wass(const float* __restrict__ Gt, const float* __restrict__ H,
                       const float* __restrict__ B2, const float* __restrict__ D21,
                       const float* __restrict__ D22, const float* __restrict__ Fx,
                       float* __restrict__ W1, float* __restrict__ W2, float* __restrict__ bias) {
  int idx = blockIdx.x * 256 + threadIdx.x;
  if (idx < 16384) {
    int o = idx >> 7, j = idx & 127;
    float s = 0.f;
    for (int a = 0; a < 512; ++a) s = fmaf(Gt[a * 128 + o], H[(640 + a) * 1152 + 512 + j], s);
    W1[idx] = s + D21[idx];
  } else if (idx < 32768) {
    int q = idx - 16384;
    int o = q >> 7, j = q & 127;
    float s = 0.f;
    for (int a = 0; a < 512; ++a) s = fmaf(Gt[a * 128 + o], B2[a * 128 + j], s);
    W2[q] = s + D22[q];
  } else if (idx < 32768 + 128) {
    int o = idx - 32768;
    float s = 0.f;
    for (int a = 0; a < 512; ++a) s = fmaf(Gt[a * 128 + o], Fx[a], s);
    bias[o] = s;
  }
}

// ---------------- baseT[i][b] = xc[i] + (u @ D12^T)[b][i] ----------------
__global__ __launch_bounds__(256) void k_ud(const float* __restrict__ u, const float* __restrict__ D12,
                                            const float* __restrict__ xc, float* __restrict__ baseT) {
  __shared__ float sU[32][65]; // [k][m=b]
  __shared__ float sD[32][65]; // [k][n=i]
  const int t = threadIdx.x;
  const int b0 = blockIdx.x * 64, i0 = blockIdx.y * 64;
  const int tm = t & 15, tn = t >> 4;
  float acc[4][4] = {}; // [n][m]
  for (int k0 = 0; k0 < 128; k0 += 32) {
    #pragma unroll
    for (int l = 0; l < 2; ++l) {
      int idx = t + l * 256;
      int row = idx >> 3, k4 = (idx & 7) << 2;
      float4 v = *(const float4*)&u[(b0 + row) * 128 + k0 + k4];
      sU[k4 + 0][row] = v.x; sU[k4 + 1][row] = v.y; sU[k4 + 2][row] = v.z; sU[k4 + 3][row] = v.w;
      float4 d = *(const float4*)&D12[(i0 + row) * 128 + k0 + k4];
      sD[k4 + 0][row] = d.x; sD[k4 + 1][row] = d.y; sD[k4 + 2][row] = d.z; sD[k4 + 3][row] = d.w;
    }
    __syncthreads();
    #pragma unroll
    for (int kk = 0; kk < 32; ++kk) {
      float mm[4], nn[4];
      #pragma unroll
      for (int q = 0; q < 4; ++q) mm[q] = sU[kk][tm * 4 + q];
      #pragma unroll
      for (int q = 0; q < 4; ++q) nn[q] = sD[kk][tn * 4 + q];
      #pragma unroll
      for (int c = 0; c < 4; ++c)
        #pragma unroll
        for (int r = 0; r < 4; ++r)
          acc[c][r] = fmaf(nn[c], mm[r], acc[c][r]);
    }
    __syncthreads();
  }
  #pragma unroll
  for (int c = 0; c < 4; ++c) {
    int i = i0 + tn * 4 + c;
    float xcv = xc[i];
    float4 v = make_float4(acc[c][0] + xcv, acc[c][1] + xcv, acc[c][2] + xcv, acc[c][3] + xcv);
    *(float4*)&baseT[i * BATCH + b0 + tm * 4] = v;
  }
}

// ---------------- scan (in place: wT over baseT) ----------------
__global__ __launch_bounds__(64) void k_scan(const float* __restrict__ baseT, const float* __restrict__ D11g,
                                             const float* __restrict__ Lam, float* __restrict__ wT) {
  __shared__ float sD[128 * 128];
  __shared__ float srl[128];
  const int tid = threadIdx.x;
  for (int l = 0; l < 64; ++l) {
    int idx = tid + l * 64;
    *(float4*)&sD[idx * 4] = *(const float4*)&D11g[idx * 4];
  }
  #pragma unroll
  for (int l = 0; l < 2; ++l) {
    int i = tid + l * 64;
    srl[i] = 1.0f / Lam[i];
  }
  __syncthreads();
  const int b = blockIdx.x * 64 + tid;
  float w[128];
  #pragma unroll
  for (int i = 0; i < 128; ++i) {
    float acc = baseT[i * BATCH + b];
    #pragma unroll
    for (int j = 0; j < i; ++j) acc = fmaf(w[j], sD[i * 128 + j], acc);
    w[i] = tanhf(acc * srl[i]);
    wT[i * BATCH + b] = w[i];
  }
}

// ---------------- y = w@W1^T + u@W2^T + bias ----------------
__global__ __launch_bounds__(256) void k_y(const float* __restrict__ wT, const float* __restrict__ u,
                                           const float* __restrict__ W1, const float* __restrict__ W2,
                                           const float* __restrict__ bias, float* __restrict__ y) {
  __shared__ float sA[32][65]; // [k][m=b]
  __shared__ float sW[32][65]; // [k][n=o]
  const int t = threadIdx.x;
  const int b0 = blockIdx.x * 64, o0 = blockIdx.y * 64;
  const int tn = t & 15, tm = t >> 4;
  float acc[4][4] = {}; // [m][n]
  for (int k0 = 0; k0 < 128; k0 += 32) {
    #pragma unroll
    for (int l = 0; l < 2; ++l) {
      int idx = t + l * 256;
      int kk = idx >> 4, c4 = (idx & 15) << 2;
      float4 v = *(const float4*)&wT[(k0 + kk) * BATCH + b0 + c4];
      sA[kk][c4 + 0] = v.x; sA[kk][c4 + 1] = v.y; sA[kk][c4 + 2] = v.z; sA[kk][c4 + 3] = v.w;
      int row = idx >> 3, k4 = (idx & 7) << 2;
      float4 d = *(const float4*)&W1[(o0 + row) * 128 + k0 + k4];
      sW[k4 + 0][row] = d.x; sW[k4 + 1][row] = d.y; sW[k4 + 2][row] = d.z; sW[k4 + 3][row] = d.w;
    }
    __syncthreads();
    #pragma unroll
    for (int kk = 0; kk < 32; ++kk) {
      float mm[4], nn[4];
      #pragma unroll
      for (int q = 0; q < 4; ++q) mm[q] = sA[kk][tm * 4 + q];
      #pragma unroll
      for (int q = 0; q < 4; ++q) nn[q] = sW[kk][tn * 4 + q];
      #pragma unroll
      for (int r = 0; r < 4; ++r)
        #pragma unroll
        for (int c = 0; c < 4; ++c)
          acc[r][c] = fmaf(mm[r], nn[c], acc[r][c]);
    }
    __syncthreads();
  }
  for (int k0 = 0; k0 < 128; k0 += 32) {
    #pragma unroll
    for (int l = 0; l < 2; ++l) {
      int idx = t + l * 256;
      int row = idx >> 3, k4 = (idx & 7) << 2;
      float4 v = *(const float4*)&u[(b0 + row) * 128 + k0 + k4];
      sA[k4 + 0][row] = v.x; sA[k4 + 1][row] = v.y; sA[k4 + 2][row] = v.z; sA[k4 + 3][row] = v.w;
      float4 d = *(const float4*)&W2[(o0 + row) * 128 + k0 + k4];
      sW[k4 + 0][row] = d.x; sW[k4 + 1][row] = d.y; sW[k4 + 2][row] = d.z; sW[k4 + 3][row] = d.w;
    }
    __syncthreads();
    #pragma unroll
    for (int kk = 0; kk < 32; ++kk) {
      float mm[4], nn[4];
      #pragma unroll
      for (int q = 0; q < 4; ++q) mm[q] = sA[kk][tm * 4 + q];
      #pragma unroll
      for (int q = 0; q < 4; ++q) nn[q] = sW[kk][tn * 4 + q];
      #pragma unroll
      for (int r = 0; r < 4; ++r)
        #pragma unroll
        for (int c = 0; c < 4; ++c)
          acc[r][c] = fmaf(mm[r], nn[c], acc[r][c]);
    }
    __syncthreads();
  }
  #pragma unroll
  for (int r = 0; r < 4; ++r) {
    int bb = b0 + tm * 4 + r;
    float4 v = make_float4(acc[r][0] + bias[o0 + tn * 4 + 0],
                           acc[r][1] + bias[o0 + tn * 4 + 1],
                           acc[r][2] + bias[o0 + tn * 4 + 2],
                           acc[r][3] + bias[o0 + tn * 4 + 3]);
    *(float4*)&y[bb * 128 + o0 + tn * 4] = v;
  }
}

extern "C" void kernel_launch(void* const* d_in, const int* in_sizes, int n_in,
                              void* d_out, int out_size, void* d_ws, size_t ws_size,
                              hipStream_t stream) {
  const float* u   = (const float*)d_in[0];
  const float* X   = (const float*)d_in[1];
  const float* Y   = (const float*)d_in[2];
  const float* B2  = (const float*)d_in[3];
  const float* C2  = (const float*)d_in[4];
  const float* D21 = (const float*)d_in[5];
  const float* D22 = (const float*)d_in[6];
  const float* D12 = (const float*)d_in[7];
  const float* x0  = (const float*)d_in[8];

  float* ws = (float*)d_ws;
  float* H     = ws;                    // 1152*1152 = 1327104
  float* Ut    = H;                     // alias: 512*512 = 262144 (overwrites dead H11 region after k_assemble)
  float* M     = H + 1327104;           // 512*640 = 327680
  float* Gt    = M + 327680;            // 512*128 = 65536
  float* W1    = Gt + 65536;            // 16384
  float* W2    = W1 + 16384;            // 16384
  float* D11   = W2 + 16384;            // 16384
  float* Lam   = D11 + 16384;           // 128
  float* rdU   = Lam + 128;             // 512
  float* xc    = rdU + 512;             // 128
  float* Fx    = xc + 128;              // 512
  float* bias  = Fx + 512;              // 128
  float* baseT = bias + 128;            // 128*16384 = 2097152
  float* wT    = baseT;                 // in-place
  float* y     = (float*)d_out;

  k_xtx<<<dim3(18, 18), 256, 0, stream>>>(X, H);
  k_assemble<<<1347, 256, 0, stream>>>(H, Y, C2, x0, M, D11, Lam, xc, Fx);

  for (int kb = 0; kb < 8; ++kb) {
    k_lu_diag<<<1, 64, 0, stream>>>(M, Ut, rdU, kb);
    k_lu_panels<<<16 - 2 * kb, 64, 0, stream>>>(M, Ut, kb);
    if (kb < 7)
      k_lu_trailing<<<dim3(9 - kb, 7 - kb), 256, 0, stream>>>(M, kb);
  }

  k_trsm_bwd<<<32, 256, 0, stream>>>(M, Ut, rdU, Gt);
  k_wass<<<129, 256, 0, stream>>>(Gt, H, B2, D21, D22, Fx, W1, W2, bias);

  k_ud<<<dim3(256, 2), 256, 0, stream>>>(u, D12, xc, baseT);
  k_scan<<<256, 64, 0, stream>>>(baseT, D11, Lam, wT);
  k_y<<<dim3(256, 2), 256, 0, stream>>>(wT, u, W1, W2, bias, y);
}

// Round 3
// 1071.659 us; speedup vs baseline: 1.6325x; 1.6325x over previous
//
#include <hip/hip_runtime.h>
#include <math.h>

#define EPS_C 0.001f
#define BATCH 16384
#define FLAG_SIG 0x600D0000

// ---------------- H = X^T X + eps*I  (1152x1152) ----------------
__global__ __launch_bounds__(256) void k_xtx(const float* __restrict__ X, float* __restrict__ H) {
  __shared__ float sA[32][65];
  __shared__ float sB[32][65];
  const int t = threadIdx.x;
  const int bi = blockIdx.x * 64, bj = blockIdx.y * 64;
  const int tj = t & 15, ti = t >> 4;
  float acc[4][4] = {};
  for (int k0 = 0; k0 < 1152; k0 += 32) {
    #pragma unroll
    for (int l = 0; l < 2; ++l) {
      int idx = t + l * 256;
      int kk = idx >> 4, c4 = (idx & 15) << 2;
      float4 va = *(const float4*)&X[(k0 + kk) * 1152 + bi + c4];
      sA[kk][c4 + 0] = va.x; sA[kk][c4 + 1] = va.y; sA[kk][c4 + 2] = va.z; sA[kk][c4 + 3] = va.w;
      float4 vb = *(const float4*)&X[(k0 + kk) * 1152 + bj + c4];
      sB[kk][c4 + 0] = vb.x; sB[kk][c4 + 1] = vb.y; sB[kk][c4 + 2] = vb.z; sB[kk][c4 + 3] = vb.w;
    }
    __syncthreads();
    #pragma unroll
    for (int kk = 0; kk < 32; ++kk) {
      float am[4], bn[4];
      #pragma unroll
      for (int q = 0; q < 4; ++q) am[q] = sA[kk][ti * 4 + q];
      #pragma unroll
      for (int q = 0; q < 4; ++q) bn[q] = sB[kk][tj * 4 + q];
      #pragma unroll
      for (int r = 0; r < 4; ++r)
        #pragma unroll
        for (int c = 0; c < 4; ++c)
          acc[r][c] = fmaf(am[r], bn[c], acc[r][c]);
    }
    __syncthreads();
  }
  #pragma unroll
  for (int r = 0; r < 4; ++r) {
    int gi = bi + ti * 4 + r;
    float vv[4];
    #pragma unroll
    for (int c = 0; c < 4; ++c) {
      vv[c] = acc[r][c];
      if (gi == bj + tj * 4 + c) vv[c] += EPS_C;
    }
    float4 o = make_float4(vv[0], vv[1], vv[2], vv[3]);
    *(float4*)&H[gi * 1152 + bj + tj * 4] = o;
  }
}

// ---------------- assemble M=[E^T | C2^T], D11, Lam, xc, Fx ----------------
// blocks 0..255: E^T 32x32 tiles (transposed reads staged via LDS)
// blocks 256..319: C2^T copy; 320..383: D11; 384: Lam; 385: xc; 386..387: Fx
__global__ __launch_bounds__(256) void k_assemble(const float* __restrict__ H, const float* __restrict__ Y,
                           const float* __restrict__ C2, const float* __restrict__ x0,
                           float* __restrict__ M, float* __restrict__ D11,
                           float* __restrict__ Lam, float* __restrict__ xc, float* __restrict__ Fx) {
  const int b = blockIdx.x;
  const int t = threadIdx.x;
  if (b < 256) {
    __shared__ float tA[32][33], tB[32][33], tC[32][33];
    const int R0 = (b & 15) * 32, C0 = (b >> 4) * 32;
    const int c = t & 31, rr = t >> 5;
    #pragma unroll
    for (int p = 0; p < 4; ++p) {
      int row = rr + p * 8; // local cc index
      tA[row][c] = H[(C0 + row) * 1152 + R0 + c];
      tB[row][c] = H[(640 + C0 + row) * 1152 + 640 + R0 + c];
      tC[row][c] = Y[(C0 + row) * 512 + R0 + c];
    }
    __syncthreads();
    #pragma unroll
    for (int p = 0; p < 4; ++p) {
      int r = rr + p * 8; // local row
      float val = 0.5f * (tA[c][r] + tB[c][r] + tC[c][r] - Y[(R0 + r) * 512 + C0 + c]);
      M[(R0 + r) * 640 + C0 + c] = val;
    }
  } else if (b < 320) {
    int e0 = (b - 256) * 1024;
    #pragma unroll
    for (int l = 0; l < 4; ++l) {
      int e = e0 + l * 256 + t;
      int r = e >> 7, o = e & 127;
      M[r * 640 + 512 + o] = C2[o * 512 + r];
    }
  } else if (b < 384) {
    int e = (b - 320) * 256 + t;
    int i = e >> 7, j = e & 127;
    D11[e] = (j < i) ? -H[(512 + i) * 1152 + 512 + j] : 0.0f;
  } else if (b == 384) {
    if (t < 128) Lam[t] = 0.5f * H[(512 + t) * 1152 + 512 + t];
  } else if (b == 385) {
    if (t < 128) {
      float s = 0.f;
      for (int a = 0; a < 512; ++a) s = fmaf(H[(512 + t) * 1152 + a], x0[a], s);
      xc[t] = -s;
    }
  } else {
    int r = (b - 386) * 256 + t;
    float s = 0.f;
    for (int a = 0; a < 512; ++a) s = fmaf(H[(640 + r) * 1152 + a], x0[a], s);
    Fx[r] = s;
  }
}

// ---------------- LU diag block factor (no pivoting) ----------------
__global__ __launch_bounds__(64) void k_lu_diag(float* __restrict__ M, int kb) {
  const int lane = threadIdx.x;
  float* blk = M + kb * 64 * 640 + kb * 64;
  float col[64];
  #pragma unroll
  for (int r = 0; r < 64; ++r) col[r] = blk[r * 640 + lane];
  float invp = 1.0f;
  #pragma unroll
  for (int k = 0; k < 64; ++k) {
    float piv = __shfl(col[k], k);
    float inv = 1.0f / piv;
    if (lane == k) invp = inv;
    float m = col[k] * inv;
    bool act = lane > k;
    #pragma unroll
    for (int r = k + 1; r < 64; ++r) {
      float ckr = __shfl(col[r], k);
      if (act) col[r] -= ckr * m;
    }
  }
  #pragma unroll
  for (int r = 0; r < 64; ++r) {
    if (r > lane) col[r] *= invp;
    blk[r * 640 + lane] = col[r];
  }
}

// ---------------- panels: per-thread fully-unrolled 64-deep triangular solves ----------------
__global__ __launch_bounds__(64) void k_lu_panels(float* __restrict__ M, int kb) {
  __shared__ float sD[64 * 65];
  __shared__ float sRD[64];
  const int t = threadIdx.x;
  for (int l = 0; l < 64; ++l) sD[l * 65 + t] = M[(kb * 64 + l) * 640 + kb * 64 + t];
  __syncthreads();
  sRD[t] = 1.0f / sD[t * 65 + t];
  __syncthreads();
  const int nU = 9 - kb;
  const int b = blockIdx.x;
  if (b < nU) {
    const int c = 64 * (kb + 1) + b * 64 + t;
    float v[64];
    #pragma unroll
    for (int i = 0; i < 64; ++i) v[i] = M[(kb * 64 + i) * 640 + c];
    #pragma unroll
    for (int i = 1; i < 64; ++i) {
      float a0 = v[i], a1 = 0.f;
      #pragma unroll
      for (int j = 0; j < i; j += 2) {
        a0 = fmaf(-sD[i * 65 + j], v[j], a0);
        if (j + 1 < i) a1 = fmaf(-sD[i * 65 + j + 1], v[j + 1], a1);
      }
      v[i] = a0 + a1;
    }
    #pragma unroll
    for (int i = 0; i < 64; ++i) M[(kb * 64 + i) * 640 + c] = v[i];
  } else {
    const int r = 64 * (kb + 1) + (b - nU) * 64 + t;
    float v[64];
    #pragma unroll
    for (int i = 0; i < 16; ++i) *(float4*)&v[i * 4] = *(const float4*)&M[r * 640 + kb * 64 + i * 4];
    #pragma unroll
    for (int j = 0; j < 64; ++j) {
      float a0 = v[j], a1 = 0.f;
      #pragma unroll
      for (int i = 0; i < j; i += 2) {
        a0 = fmaf(-v[i], sD[i * 65 + j], a0);
        if (i + 1 < j) a1 = fmaf(-v[i + 1], sD[(i + 1) * 65 + j], a1);
      }
      v[j] = (a0 + a1) * sRD[j];
    }
    #pragma unroll
    for (int i = 0; i < 16; ++i) *(float4*)&M[r * 640 + kb * 64 + i * 4] = *(float4*)&v[i * 4];
  }
}

// ---------------- trailing update: A22 -= L21 * U12 (cols include augmented) ----------------
__global__ __launch_bounds__(256) void k_lu_trailing(float* __restrict__ M, int kb) {
  __shared__ float sL[32][65];
  __shared__ float sU[32][65];
  const int t = threadIdx.x;
  const int base = 64 * (kb + 1);
  const int r0 = base + blockIdx.y * 64, c0 = base + blockIdx.x * 64;
  const int tj = t & 15, ti = t >> 4;
  float acc[4][4] = {};
  for (int k0 = 0; k0 < 64; k0 += 32) {
    #pragma unroll
    for (int l = 0; l < 2; ++l) {
      int idx = t + l * 256;
      int row = idx >> 3, k4 = (idx & 7) << 2;
      float4 v = *(const float4*)&M[(r0 + row) * 640 + kb * 64 + k0 + k4];
      sL[k4 + 0][row] = v.x; sL[k4 + 1][row] = v.y; sL[k4 + 2][row] = v.z; sL[k4 + 3][row] = v.w;
      int kk = idx >> 4, c4 = (idx & 15) << 2;
      float4 u4 = *(const float4*)&M[(kb * 64 + k0 + kk) * 640 + c0 + c4];
      sU[kk][c4 + 0] = u4.x; sU[kk][c4 + 1] = u4.y; sU[kk][c4 + 2] = u4.z; sU[kk][c4 + 3] = u4.w;
    }
    __syncthreads();
    #pragma unroll
    for (int kk = 0; kk < 32; ++kk) {
      float am[4], bn[4];
      #pragma unroll
      for (int q = 0; q < 4; ++q) am[q] = sL[kk][ti * 4 + q];
      #pragma unroll
      for (int q = 0; q < 4; ++q) bn[q] = sU[kk][tj * 4 + q];
      #pragma unroll
      for (int r = 0; r < 4; ++r)
        #pragma unroll
        for (int c = 0; c < 4; ++c)
          acc[r][c] = fmaf(am[r], bn[c], acc[r][c]);
    }
    __syncthreads();
  }
  #pragma unroll
  for (int r = 0; r < 4; ++r) {
    float4 old = *(float4*)&M[(r0 + ti * 4 + r) * 640 + c0 + tj * 4];
    old.x -= acc[r][0]; old.y -= acc[r][1]; old.z -= acc[r][2]; old.w -= acc[r][3];
    *(float4*)&M[(r0 + ti * 4 + r) * 640 + c0 + tj * 4] = old;
  }
}

// ---------------- backward solve U * Gt = Z : single launch, 8 blocks, spin-flag chained ----------------
__global__ __launch_bounds__(512) void k_bs(float* __restrict__ M, float* __restrict__ Gt, int* __restrict__ flags) {
  __shared__ float sU[64 * 65];
  __shared__ float sX[64 * 128];
  __shared__ float srs[64];
  const int kb = blockIdx.x;       // row block owned
  const int t = threadIdx.x;
  const int o = t & 127, q = t >> 7;
  float z[16];
  #pragma unroll
  for (int r = 0; r < 16; ++r) z[r] = M[(kb * 64 + q * 16 + r) * 640 + 512 + o];

  for (int j = 7; j > kb; --j) {
    if (t == 0) {
      while (__hip_atomic_load(&flags[j], __ATOMIC_ACQUIRE, __HIP_MEMORY_SCOPE_AGENT) != (FLAG_SIG + j)) {}
    }
    __syncthreads();
    // stage U_{kb,j} and X_j
    #pragma unroll
    for (int l = 0; l < 8; ++l) {
      int e = t + l * 512;
      int r = e >> 6, k = e & 63;
      sU[r * 65 + k] = M[(kb * 64 + r) * 640 + j * 64 + k];
    }
    #pragma unroll
    for (int l = 0; l < 16; ++l) {
      int e = t + l * 512;
      int k = e >> 7, o2 = e & 127;
      sX[k * 128 + o2] = Gt[(j * 64 + k) * 128 + o2];
    }
    __syncthreads();
    for (int k = 0; k < 64; ++k) {
      float xk = sX[k * 128 + o];
      #pragma unroll
      for (int r = 0; r < 16; ++r)
        z[r] = fmaf(-sU[(q * 16 + r) * 65 + k], xk, z[r]);
    }
    __syncthreads();
  }

  // dump z to LDS (reuse sX as Z), stage diag block, solve
  #pragma unroll
  for (int r = 0; r < 16; ++r) sX[(q * 16 + r) * 128 + o] = z[r];
  #pragma unroll
  for (int l = 0; l < 8; ++l) {
    int e = t + l * 512;
    int r = e >> 6, k = e & 63;
    sU[r * 65 + k] = M[(kb * 64 + r) * 640 + kb * 64 + k];
  }
  __syncthreads();
  if (t < 64) srs[t] = 1.0f / sU[t * 65 + t];
  __syncthreads();
  if (t < 128) {
    float v[64];
    #pragma unroll
    for (int i = 0; i < 64; ++i) v[i] = sX[i * 128 + t];
    #pragma unroll
    for (int i = 63; i >= 0; --i) {
      float a0 = v[i], a1 = 0.f;
      #pragma unroll
      for (int jj = i + 1; jj < 64; jj += 2) {
        a0 = fmaf(-sU[i * 65 + jj], v[jj], a0);
        if (jj + 1 < 64) a1 = fmaf(-sU[i * 65 + jj + 1], v[jj + 1], a1);
      }
      v[i] = (a0 + a1) * srs[i];
    }
    #pragma unroll
    for (int i = 0; i < 64; ++i) Gt[(kb * 64 + i) * 128 + t] = v[i];
  }
  __threadfence();
  __syncthreads();
  if (t == 0)
    __hip_atomic_store(&flags[kb], FLAG_SIG + kb, __ATOMIC_RELEASE, __HIP_MEMORY_SCOPE_AGENT);
}

// ---------------- W1 = G@B1 + D21, W2 = G@B2 + D22, bias = G@Fx ----------------
__global__ void k_wass(const float* __restrict__ Gt, const float* __restrict__ H,
                       const float* __restrict__ B2, const float* __restrict__ D21,
                       const float* __restrict__ D22, const float* __restrict__ Fx,
                       float* __restrict__ W1, float* __restrict__ W2, float* __restrict__ bias) {
  int idx = blockIdx.x * 256 + threadIdx.x;
  if (idx < 16384) {
    int o = idx >> 7, j = idx & 127;
    float s = 0.f;
    for (int a = 0; a < 512; ++a) s = fmaf(Gt[a * 128 + o], H[(640 + a) * 1152 + 512 + j], s);
    W1[idx] = s + D21[idx];
  } else if (idx < 32768) {
    int q = idx - 16384;
    int o = q >> 7, j = q & 127;
    float s = 0.f;
    for (int a = 0; a < 512; ++a) s = fmaf(Gt[a * 128 + o], B2[a * 128 + j], s);
    W2[q] = s + D22[q];
  } else if (idx < 32768 + 128) {
    int o = idx - 32768;
    float s = 0.f;
    for (int a = 0; a < 512; ++a) s = fmaf(Gt[a * 128 + o], Fx[a], s);
    bias[o] = s;
  }
}

// ---------------- baseT[i][b] = xc[i] + (u @ D12^T)[b][i] ----------------
__global__ __launch_bounds__(256) void k_ud(const float* __restrict__ u, const float* __restrict__ D12,
                                            const float* __restrict__ xc, float* __restrict__ baseT) {
  __shared__ float sU[32][65];
  __shared__ float sD[32][65];
  const int t = threadIdx.x;
  const int b0 = blockIdx.x * 64, i0 = blockIdx.y * 64;
  const int tm = t & 15, tn = t >> 4;
  float acc[4][4] = {};
  for (int k0 = 0; k0 < 128; k0 += 32) {
    #pragma unroll
    for (int l = 0; l < 2; ++l) {
      int idx = t + l * 256;
      int row = idx >> 3, k4 = (idx & 7) << 2;
      float4 v = *(const float4*)&u[(b0 + row) * 128 + k0 + k4];
      sU[k4 + 0][row] = v.x; sU[k4 + 1][row] = v.y; sU[k4 + 2][row] = v.z; sU[k4 + 3][row] = v.w;
      float4 d = *(const float4*)&D12[(i0 + row) * 128 + k0 + k4];
      sD[k4 + 0][row] = d.x; sD[k4 + 1][row] = d.y; sD[k4 + 2][row] = d.z; sD[k4 + 3][row] = d.w;
    }
    __syncthreads();
    #pragma unroll
    for (int kk = 0; kk < 32; ++kk) {
      float mm[4], nn[4];
      #pragma unroll
      for (int q = 0; q < 4; ++q) mm[q] = sU[kk][tm * 4 + q];
      #pragma unroll
      for (int q = 0; q < 4; ++q) nn[q] = sD[kk][tn * 4 + q];
      #pragma unroll
      for (int c = 0; c < 4; ++c)
        #pragma unroll
        for (int r = 0; r < 4; ++r)
          acc[c][r] = fmaf(nn[c], mm[r], acc[c][r]);
    }
    __syncthreads();
  }
  #pragma unroll
  for (int c = 0; c < 4; ++c) {
    int i = i0 + tn * 4 + c;
    float xcv = xc[i];
    float4 v = make_float4(acc[c][0] + xcv, acc[c][1] + xcv, acc[c][2] + xcv, acc[c][3] + xcv);
    *(float4*)&baseT[i * BATCH + b0 + tm * 4] = v;
  }
}

// ---------------- scan: w[i] = tanh((base_i + sum_{j<i} D11[i][j] w[j]) / Lam[i]) ----------------
__global__ __launch_bounds__(64) void k_scan(const float* __restrict__ baseT, const float* __restrict__ D11g,
                                             const float* __restrict__ Lam, float* __restrict__ wT) {
  const int b = blockIdx.x * 64 + threadIdx.x;
  float w[128];
  #pragma unroll
  for (int i = 0; i < 128; ++i) {
    float acc0 = baseT[i * BATCH + b], acc1 = 0.f, acc2 = 0.f, acc3 = 0.f;
    const float* __restrict__ Drow = D11g + i * 128;
    #pragma unroll
    for (int j = 0; j + 4 <= i; j += 4) {
      acc0 = fmaf(w[j + 0], Drow[j + 0], acc0);
      acc1 = fmaf(w[j + 1], Drow[j + 1], acc1);
      acc2 = fmaf(w[j + 2], Drow[j + 2], acc2);
      acc3 = fmaf(w[j + 3], Drow[j + 3], acc3);
    }
    #pragma unroll
    for (int j = i & ~3; j < i; ++j) acc0 = fmaf(w[j], Drow[j], acc0);
    float zv = ((acc0 + acc1) + (acc2 + acc3)) / Lam[i];
    float az = fabsf(zv);
    float e = __expf(-2.0f * az);
    float th = (1.0f - e) / (1.0f + e);
    w[i] = copysignf(th, zv);
    wT[i * BATCH + b] = w[i];
  }
}

// ---------------- y = w@W1^T + u@W2^T + bias ----------------
__global__ __launch_bounds__(256) void k_y(const float* __restrict__ wT, const float* __restrict__ u,
                                           const float* __restrict__ W1, const float* __restrict__ W2,
                                           const float* __restrict__ bias, float* __restrict__ y) {
  __shared__ float sA[32][65];
  __shared__ float sW[32][65];
  const int t = threadIdx.x;
  const int b0 = blockIdx.x * 64, o0 = blockIdx.y * 64;
  const int tn = t & 15, tm = t >> 4;
  float acc[4][4] = {};
  for (int k0 = 0; k0 < 128; k0 += 32) {
    #pragma unroll
    for (int l = 0; l < 2; ++l) {
      int idx = t + l * 256;
      int kk = idx >> 4, c4 = (idx & 15) << 2;
      float4 v = *(const float4*)&wT[(k0 + kk) * BATCH + b0 + c4];
      sA[kk][c4 + 0] = v.x; sA[kk][c4 + 1] = v.y; sA[kk][c4 + 2] = v.z; sA[kk][c4 + 3] = v.w;
      int row = idx >> 3, k4 = (idx & 7) << 2;
      float4 d = *(const float4*)&W1[(o0 + row) * 128 + k0 + k4];
      sW[k4 + 0][row] = d.x; sW[k4 + 1][row] = d.y; sW[k4 + 2][row] = d.z; sW[k4 + 3][row] = d.w;
    }
    __syncthreads();
    #pragma unroll
    for (int kk = 0; kk < 32; ++kk) {
      float mm[4], nn[4];
      #pragma unroll
      for (int q = 0; q < 4; ++q) mm[q] = sA[kk][tm * 4 + q];
      #pragma unroll
      for (int q = 0; q < 4; ++q) nn[q] = sW[kk][tn * 4 + q];
      #pragma unroll
      for (int r = 0; r < 4; ++r)
        #pragma unroll
        for (int c = 0; c < 4; ++c)
          acc[r][c] = fmaf(mm[r], nn[c], acc[r][c]);
    }
    __syncthreads();
  }
  for (int k0 = 0; k0 < 128; k0 += 32) {
    #pragma unroll
    for (int l = 0; l < 2; ++l) {
      int idx = t + l * 256;
      int row = idx >> 3, k4 = (idx & 7) << 2;
      float4 v = *(const float4*)&u[(b0 + row) * 128 + k0 + k4];
      sA[k4 + 0][row] = v.x; sA[k4 + 1][row] = v.y; sA[k4 + 2][row] = v.z; sA[k4 + 3][row] = v.w;
      float4 d = *(const float4*)&W2[(o0 + row) * 128 + k0 + k4];
      sW[k4 + 0][row] = d.x; sW[k4 + 1][row] = d.y; sW[k4 + 2][row] = d.z; sW[k4 + 3][row] = d.w;
    }
    __syncthreads();
    #pragma unroll
    for (int kk = 0; kk < 32; ++kk) {
      float mm[4], nn[4];
      #pragma unroll
      for (int q = 0; q < 4; ++q) mm[q] = sA[kk][tm * 4 + q];
      #pragma unroll
      for (int q = 0; q < 4; ++q) nn[q] = sW[kk][tn * 4 + q];
      #pragma unroll
      for (int r = 0; r < 4; ++r)
        #pragma unroll
        for (int c = 0; c < 4; ++c)
          acc[r][c] = fmaf(mm[r], nn[c], acc[r][c]);
    }
    __syncthreads();
  }
  #pragma unroll
  for (int r = 0; r < 4; ++r) {
    int bb = b0 + tm * 4 + r;
    float4 v = make_float4(acc[r][0] + bias[o0 + tn * 4 + 0],
                           acc[r][1] + bias[o0 + tn * 4 + 1],
                           acc[r][2] + bias[o0 + tn * 4 + 2],
                           acc[r][3] + bias[o0 + tn * 4 + 3]);
    *(float4*)&y[bb * 128 + o0 + tn * 4] = v;
  }
}

extern "C" void kernel_launch(void* const* d_in, const int* in_sizes, int n_in,
                              void* d_out, int out_size, void* d_ws, size_t ws_size,
                              hipStream_t stream) {
  const float* u   = (const float*)d_in[0];
  const float* X   = (const float*)d_in[1];
  const float* Y   = (const float*)d_in[2];
  const float* B2  = (const float*)d_in[3];
  const float* C2  = (const float*)d_in[4];
  const float* D21 = (const float*)d_in[5];
  const float* D22 = (const float*)d_in[6];
  const float* D12 = (const float*)d_in[7];
  const float* x0  = (const float*)d_in[8];

  float* ws = (float*)d_ws;
  float* H     = ws;                    // 1327104
  float* M     = H + 1327104;           // 512*640 = 327680
  float* Gt    = M + 327680;            // 65536
  float* W1    = Gt + 65536;            // 16384
  float* W2    = W1 + 16384;            // 16384
  float* D11   = W2 + 16384;            // 16384
  float* Lam   = D11 + 16384;           // 128
  float* xc    = Lam + 128;             // 128
  float* Fx    = xc + 128;              // 512
  float* bias  = Fx + 512;              // 128
  int*   flags = (int*)(bias + 128);    // 8
  float* baseT = bias + 128 + 64;       // 128*16384 = 2097152
  float* wT    = baseT;                 // in-place
  float* y     = (float*)d_out;

  k_xtx<<<dim3(18, 18), 256, 0, stream>>>(X, H);
  k_assemble<<<388, 256, 0, stream>>>(H, Y, C2, x0, M, D11, Lam, xc, Fx);

  for (int kb = 0; kb < 8; ++kb) {
    k_lu_diag<<<1, 64, 0, stream>>>(M, kb);
    k_lu_panels<<<16 - 2 * kb, 64, 0, stream>>>(M, kb);
    if (kb < 7)
      k_lu_trailing<<<dim3(9 - kb, 7 - kb), 256, 0, stream>>>(M, kb);
  }

  k_bs<<<8, 512, 0, stream>>>(M, Gt, flags);
  k_wass<<<129, 256, 0, stream>>>(Gt, H, B2, D21, D22, Fx, W1, W2, bias);

  k_ud<<<dim3(256, 2), 256, 0, stream>>>(u, D12, xc, baseT);
  k_scan<<<256, 64, 0, stream>>>(baseT, D11, Lam, wT);
  k_y<<<dim3(256, 2), 256, 0, stream>>>(wT, u, W1, W2, bias, y);
}